// Round 20
// baseline (31.849 us; speedup 1.0000x reference)
//
#include <hip/hip_runtime.h>

#define BATCH 4
#define NPTS  8192
#define BN    (BATCH * NPTS)   // 32768

typedef _Float16 f16;
typedef f16   f16x4  __attribute__((ext_vector_type(4)));
typedef f16   f16x8  __attribute__((ext_vector_type(8)));
typedef float f32x16 __attribute__((ext_vector_type(16)));

// order-preserving float <-> uint for unsigned atomicMin
__device__ __forceinline__ unsigned fkey(float f) {
    unsigned u = __float_as_uint(f);
    return u ^ (unsigned)(((int)u >> 31) | 0x80000000);
}
__device__ __forceinline__ float funkey(unsigned k) {
    unsigned u = k ^ ((k & 0x80000000u) ? 0x80000000u : 0xFFFFFFFFu);
    return __uint_as_float(u);
}

// min of 16 f32 via v_min3 tree
__device__ __forceinline__ float min16(const f32x16& d) {
    float t0 = fminf(fminf(d[0],  d[1]),  d[2]);
    float t1 = fminf(fminf(d[3],  d[4]),  d[5]);
    float t2 = fminf(fminf(d[6],  d[7]),  d[8]);
    float t3 = fminf(fminf(d[9],  d[10]), d[11]);
    float t4 = fminf(fminf(d[12], d[13]), d[14]);
    float t5 = fminf(fminf(t0, t1), d[15]);
    float t6 = fminf(fminf(t2, t3), t4);
    return fminf(t5, t6);
}

// 32x32x8 f16 MFMA (K=8 covers our 5 live K-slots)
__device__ __forceinline__ f32x16 mfma8(f16x4 a, f16x4 b, f32x16 c) {
#if defined(__has_builtin) && __has_builtin(__builtin_amdgcn_mfma_f32_32x32x8f16)
    return __builtin_amdgcn_mfma_f32_32x32x8f16(a, b, c, 0, 0, 0);
#else
    f32x16 d;
    asm volatile("v_mfma_f32_32x32x8_f16 %0, %1, %2, %3"
                 : "=v"(d) : "v"(a), "v"(b), "v"(c));
    return d;
#endif
}

// ---- pack+init: point -> f16x8 {-2x,-2y,-2z, csq_hi, csq_lo, 0,0,0} -------
// Also initializes keys (one word per thread) and out. grid: (BN/256, 2) x 256
__global__ void pack_kernel(const float* __restrict__ preds,
                            const float* __restrict__ gts,
                            f16x8* __restrict__ cP,
                            f16x8* __restrict__ cG,
                            unsigned* __restrict__ keys,
                            float* __restrict__ out) {
    const int i     = blockIdx.x * 256 + threadIdx.x;
    const int which = blockIdx.y;

    keys[(size_t)which * BN + i] = 0xFFFFFFFFu;   // +inf key

    if (which == 0 && i == 0) *out = 0.0f;

    const float* src = which ? gts : preds;
    f16x8* dst       = which ? cG : cP;
    float x = src[3 * i], y = src[3 * i + 1], z = src[3 * i + 2];
    f16 xh = (f16)x, yh = (f16)y, zh = (f16)z;
    float xf = (float)xh, yf = (float)yh, zf = (float)zh;
    float csq = xf * xf + yf * yf + zf * zf;
    f16 ch = (f16)csq;
    f16 cl = (f16)(csq - (float)ch);
    f16x8 v;
    v[0] = xh * (f16)(-2.0f);
    v[1] = yh * (f16)(-2.0f);
    v[2] = zh * (f16)(-2.0f);
    v[3] = ch;
    v[4] = cl;
    v[5] = (f16)0.0f; v[6] = (f16)0.0f; v[7] = (f16)0.0f;
    dst[i] = v;
}

// ---- main: A=candidates (streamed, K=8), B=8 fixed query frags ------------
// R19 + deeper tile reuse: per-iteration fixed overhead is the controlling
// cost (R16->R17->R19 each paid ~1-1.5us for fewer/lighter iterations), so
// halve iteration count again: 8 B-frags, 8 iters/wave.
// Lane l: A row = cand (l&31), k slice = (l>>5): lo k0-3 {-2x,-2y,-2z,ch},
// hi k4-7 {cl,0,0,0} -- 8B slice of the f16x8 pack, all 64 lanes load data.
// B col = query (l&31): lo {qx,qy,qz,1}, hi {1,0,0,0}.
// grid: 2048 x 256 (8 blocks/CU): bits [4:0]=s(32), [7:5]=qg(8), [10:8]=bd.
// Wave: 256 queries x 256 candidates, 8 iters, 64 MFMA. Live regs ~100.
__global__ void __launch_bounds__(256, 4)
chamfer_mfma_kernel(const f16x8* __restrict__ cP,
                    const f16x8* __restrict__ cG,
                    unsigned* __restrict__ keys) {
    const int lane   = threadIdx.x & 63;
    const int wavein = threadIdx.x >> 6;

    const int s   = blockIdx.x & 31;             // candidate split 0..31
    const int qg  = (blockIdx.x >> 5) & 7;       // query group 0..7
    const int bd  = blockIdx.x >> 8;             // b*2 + dir, 0..7
    const int b   = bd >> 1;
    const int dir = bd & 1;                      // 0: q=preds,c=gts ; 1: swapped

    const f16x8* __restrict__ Q = dir ? cG : cP;
    const f16x8* __restrict__ C = dir ? cP : cG;

    const bool hi  = lane >= 32;
    const int  l31 = lane & 31;

    // ---- B fragments: 8 x 32 fixed queries
    const int q0 = b * NPTS + qg * 1024 + wavein * 256;
    f16x4 bq0, bq1, bq2, bq3, bq4, bq5, bq6, bq7;
    float qsq0, qsq1, qsq2, qsq3, qsq4, qsq5, qsq6, qsq7;
    {
        const f16 nh  = (f16)(-0.5f);            // -0.5 * (-2x) = x, exact
        const f16 one = (f16)1.0f;
        const f16 zz  = (f16)0.0f;
#define MKB(bq, qsq, OFS)                                              \
        {                                                              \
            f16x8 qr = Q[q0 + (OFS) + l31];                            \
            qsq = (float)qr[3] + (float)qr[4];                         \
            bq[0] = hi ? one : qr[0] * nh;                             \
            bq[1] = hi ? zz  : qr[1] * nh;                             \
            bq[2] = hi ? zz  : qr[2] * nh;                             \
            bq[3] = hi ? zz  : one;                                    \
        }
        MKB(bq0, qsq0, 0)   MKB(bq1, qsq1, 32)  MKB(bq2, qsq2, 64)
        MKB(bq3, qsq3, 96)  MKB(bq4, qsq4, 128) MKB(bq5, qsq5, 160)
        MKB(bq6, qsq6, 192) MKB(bq7, qsq7, 224)
#undef MKB
    }

    // ---- A stream: 8B slice of the f16x8 pack per lane --------------------
    const int c0 = b * NPTS + s * 256;
    const f16x4* pA = (const f16x4*)((const char*)C
                        + (size_t)(c0 + l31) * 16 + (size_t)(lane >> 5) * 8);
    // advance 32 candidates = 512B = 64 f16x4 elements per iteration

    f32x16 zacc;
#pragma unroll
    for (int i = 0; i < 16; ++i) zacc[i] = 0.0f;
    float m0 = 1e30f, m1 = 1e30f, m2 = 1e30f, m3 = 1e30f;
    float m4 = 1e30f, m5 = 1e30f, m6 = 1e30f, m7 = 1e30f;

    for (int it = 0; it < 8; ++it) {             // 8 iters x 32 candidates
        f16x4 a = *pA;
        pA += 64;
        // interleave: issue next MFMA while consuming the previous d-tile,
        // so at most ~3 d-tiles are live at once (no R12 liveness trap).
        f32x16 d0 = mfma8(a, bq0, zacc);
        f32x16 d1 = mfma8(a, bq1, zacc);
        m0 = fminf(m0, min16(d0));
        f32x16 d2 = mfma8(a, bq2, zacc);
        m1 = fminf(m1, min16(d1));
        f32x16 d3 = mfma8(a, bq3, zacc);
        m2 = fminf(m2, min16(d2));
        f32x16 d4 = mfma8(a, bq4, zacc);
        m3 = fminf(m3, min16(d3));
        f32x16 d5 = mfma8(a, bq5, zacc);
        m4 = fminf(m4, min16(d4));
        f32x16 d6 = mfma8(a, bq6, zacc);
        m5 = fminf(m5, min16(d5));
        f32x16 d7 = mfma8(a, bq7, zacc);
        m6 = fminf(m6, min16(d6));
        m7 = fminf(m7, min16(d7));
    }

    // ---- epilogue: merge lane-halves, fold qsq, one atomic each -----------
    m0 = fminf(m0, __shfl_xor(m0, 32, 64));
    m1 = fminf(m1, __shfl_xor(m1, 32, 64));
    m2 = fminf(m2, __shfl_xor(m2, 32, 64));
    m3 = fminf(m3, __shfl_xor(m3, 32, 64));
    m4 = fminf(m4, __shfl_xor(m4, 32, 64));
    m5 = fminf(m5, __shfl_xor(m5, 32, 64));
    m6 = fminf(m6, __shfl_xor(m6, 32, 64));
    m7 = fminf(m7, __shfl_xor(m7, 32, 64));
    if (!hi) {
        unsigned* __restrict__ kout = keys + (size_t)dir * BN;
        atomicMin(&kout[q0 + l31],       fkey(m0 + qsq0));
        atomicMin(&kout[q0 + 32 + l31],  fkey(m1 + qsq1));
        atomicMin(&kout[q0 + 64 + l31],  fkey(m2 + qsq2));
        atomicMin(&kout[q0 + 96 + l31],  fkey(m3 + qsq3));
        atomicMin(&kout[q0 + 128 + l31], fkey(m4 + qsq4));
        atomicMin(&kout[q0 + 160 + l31], fkey(m5 + qsq5));
        atomicMin(&kout[q0 + 192 + l31], fkey(m6 + qsq6));
        atomicMin(&kout[q0 + 224 + l31], fkey(m7 + qsq7));
    }
}

// ---- finalize: decode key (qsq already folded in), global sum -------------
// grid: 2*BN/256 = 256 blocks
__global__ void __launch_bounds__(256)
finalize_kernel(const unsigned* __restrict__ keys, float* __restrict__ out) {
    __shared__ float red[4];
    const int idx = blockIdx.x * 256 + threadIdx.x;   // [0, 2*BN)

    float val = funkey(keys[idx]);

#pragma unroll
    for (int off = 32; off > 0; off >>= 1)
        val += __shfl_down(val, off, 64);

    const int wave = threadIdx.x >> 6;
    const int lane = threadIdx.x & 63;
    if (lane == 0) red[wave] = val;
    __syncthreads();
    if (threadIdx.x == 0)
        atomicAdd(out, red[0] + red[1] + red[2] + red[3]);
}

extern "C" void kernel_launch(void* const* d_in, const int* in_sizes, int n_in,
                              void* d_out, int out_size, void* d_ws, size_t ws_size,
                              hipStream_t stream) {
    const float* preds = (const float*)d_in[0];
    const float* gts   = (const float*)d_in[1];
    float* out = (float*)d_out;

    // ws layout: keys 256KB | cPackP 512KB | cPackG 512KB
    char* ws = (char*)d_ws;
    unsigned* keys = (unsigned*)ws;
    f16x8*    cP   = (f16x8*)(ws + (size_t)2 * BN * 4);
    f16x8*    cG   = cP + BN;

    dim3 gpack(BN / 256, 2);
    pack_kernel<<<gpack, 256, 0, stream>>>(preds, gts, cP, cG, keys, out);

    chamfer_mfma_kernel<<<2048, 256, 0, stream>>>(cP, cG, keys);

    finalize_kernel<<<2 * BN / 256, 256, 0, stream>>>(keys, out);
}

// Round 21
// 30.765 us; speedup vs baseline: 1.0353x; 1.0353x over previous
//
#include <hip/hip_runtime.h>

#define BATCH 4
#define NPTS  8192
#define BN    (BATCH * NPTS)   // 32768

typedef _Float16 f16;
typedef f16   f16x4  __attribute__((ext_vector_type(4)));
typedef f16   f16x8  __attribute__((ext_vector_type(8)));
typedef float f32x16 __attribute__((ext_vector_type(16)));

// order-preserving float <-> uint for unsigned atomicMin
__device__ __forceinline__ unsigned fkey(float f) {
    unsigned u = __float_as_uint(f);
    return u ^ (unsigned)(((int)u >> 31) | 0x80000000);
}
__device__ __forceinline__ float funkey(unsigned k) {
    unsigned u = k ^ ((k & 0x80000000u) ? 0x80000000u : 0xFFFFFFFFu);
    return __uint_as_float(u);
}

// min of 16 f32 via v_min3 tree
__device__ __forceinline__ float min16(const f32x16& d) {
    float t0 = fminf(fminf(d[0],  d[1]),  d[2]);
    float t1 = fminf(fminf(d[3],  d[4]),  d[5]);
    float t2 = fminf(fminf(d[6],  d[7]),  d[8]);
    float t3 = fminf(fminf(d[9],  d[10]), d[11]);
    float t4 = fminf(fminf(d[12], d[13]), d[14]);
    float t5 = fminf(fminf(t0, t1), d[15]);
    float t6 = fminf(fminf(t2, t3), t4);
    return fminf(t5, t6);
}

// 32x32x8 f16 MFMA: K=8 is enough for our 5 live K-slots -> half the matrix
// cycles and half the streamed bytes vs 32x32x16. Same 32x32 D layout
// (col = lane&31; min-then-merge is row-permutation-invariant anyway).
__device__ __forceinline__ f32x16 mfma8(f16x4 a, f16x4 b, f32x16 c) {
#if defined(__has_builtin) && __has_builtin(__builtin_amdgcn_mfma_f32_32x32x8f16)
    return __builtin_amdgcn_mfma_f32_32x32x8f16(a, b, c, 0, 0, 0);
#else
    f32x16 d;
    asm volatile("v_mfma_f32_32x32x8_f16 %0, %1, %2, %3"
                 : "=v"(d) : "v"(a), "v"(b), "v"(c));
    return d;
#endif
}

// ---- pack+init: point -> f16x8 {-2x,-2y,-2z, csq_hi, csq_lo, 0,0,0} -------
// Also initializes keys (one word per thread) and out. grid: (BN/256, 2) x 256
__global__ void pack_kernel(const float* __restrict__ preds,
                            const float* __restrict__ gts,
                            f16x8* __restrict__ cP,
                            f16x8* __restrict__ cG,
                            unsigned* __restrict__ keys,
                            float* __restrict__ out) {
    const int i     = blockIdx.x * 256 + threadIdx.x;
    const int which = blockIdx.y;

    keys[(size_t)which * BN + i] = 0xFFFFFFFFu;   // +inf key

    if (which == 0 && i == 0) *out = 0.0f;

    const float* src = which ? gts : preds;
    f16x8* dst       = which ? cG : cP;
    float x = src[3 * i], y = src[3 * i + 1], z = src[3 * i + 2];
    f16 xh = (f16)x, yh = (f16)y, zh = (f16)z;
    float xf = (float)xh, yf = (float)yh, zf = (float)zh;
    float csq = xf * xf + yf * yf + zf * zf;
    f16 ch = (f16)csq;
    f16 cl = (f16)(csq - (float)ch);
    f16x8 v;
    v[0] = xh * (f16)(-2.0f);
    v[1] = yh * (f16)(-2.0f);
    v[2] = zh * (f16)(-2.0f);
    v[3] = ch;
    v[4] = cl;
    v[5] = (f16)0.0f; v[6] = (f16)0.0f; v[7] = (f16)0.0f;
    dst[i] = v;
}

// ---- main: A=candidates (streamed, K=8), B=4 fixed query frags ------------
// Lane l: A row = cand (l&31), k = 4*(l>>5)+j. Lo lanes carry k=0..3
// {-2x,-2y,-2z,ch}; hi lanes k=4..7 {cl,0,0,0} -> both halves are an 8B slice
// of the same f16x8 pack, EVERY lane loads real data (no zero page).
// B col = query (l&31): lo {qx,qy,qz,1}, hi {1,0,0,0} (constant, no load).
// D[c,q] = csq - 2<q,c>. Per iter: 1x8B load, 4 MFMA(K=8), 4 in-reg min16.
// grid: 2048 x 256 (8 blocks/CU). Wave: 128 queries x 512 candidates, 16 iters.
// MEASURED OPTIMUM (R19: 30.96us total). R20 (8 frags) regressed: per-wave
// fixed cost outgrew the loop. R13/R18/R12 falsified occupancy/prefetch/unroll.
__global__ void __launch_bounds__(256, 4)
chamfer_mfma_kernel(const f16x8* __restrict__ cP,
                    const f16x8* __restrict__ cG,
                    unsigned* __restrict__ keys) {
    const int lane   = threadIdx.x & 63;
    const int wavein = threadIdx.x >> 6;

    const int s   = blockIdx.x & 15;             // candidate split 0..15
    const int qg  = (blockIdx.x >> 4) & 15;      // query group 0..15
    const int bd  = blockIdx.x >> 8;             // b*2 + dir, 0..7
    const int b   = bd >> 1;
    const int dir = bd & 1;                      // 0: q=preds,c=gts ; 1: swapped

    const f16x8* __restrict__ Q = dir ? cG : cP;
    const f16x8* __restrict__ C = dir ? cP : cG;

    const bool hi  = lane >= 32;
    const int  l31 = lane & 31;

    // ---- B fragments: 4 x 32 fixed queries
    const int q0 = b * NPTS + qg * 512 + wavein * 128;
    f16x4 bq0, bq1, bq2, bq3;
    float qsq0, qsq1, qsq2, qsq3;
    {
        f16x8 qr0 = Q[q0 + l31];          // hi lanes broadcast same lines
        f16x8 qr1 = Q[q0 + 32 + l31];
        f16x8 qr2 = Q[q0 + 64 + l31];
        f16x8 qr3 = Q[q0 + 96 + l31];
        qsq0 = (float)qr0[3] + (float)qr0[4];
        qsq1 = (float)qr1[3] + (float)qr1[4];
        qsq2 = (float)qr2[3] + (float)qr2[4];
        qsq3 = (float)qr3[3] + (float)qr3[4];
        const f16 nh  = (f16)(-0.5f);            // -0.5 * (-2x) = x, exact
        const f16 one = (f16)1.0f;
        const f16 zz  = (f16)0.0f;
        bq0[0] = hi ? one : qr0[0] * nh; bq0[1] = hi ? zz : qr0[1] * nh;
        bq0[2] = hi ? zz : qr0[2] * nh;  bq0[3] = hi ? zz : one;
        bq1[0] = hi ? one : qr1[0] * nh; bq1[1] = hi ? zz : qr1[1] * nh;
        bq1[2] = hi ? zz : qr1[2] * nh;  bq1[3] = hi ? zz : one;
        bq2[0] = hi ? one : qr2[0] * nh; bq2[1] = hi ? zz : qr2[1] * nh;
        bq2[2] = hi ? zz : qr2[2] * nh;  bq2[3] = hi ? zz : one;
        bq3[0] = hi ? one : qr3[0] * nh; bq3[1] = hi ? zz : qr3[1] * nh;
        bq3[2] = hi ? zz : qr3[2] * nh;  bq3[3] = hi ? zz : one;
    }

    // ---- A stream: 8B slice of the f16x8 pack per lane --------------------
    const int c0 = b * NPTS + s * 512;
    const f16x4* pA = (const f16x4*)((const char*)C
                        + (size_t)(c0 + l31) * 16 + (size_t)(lane >> 5) * 8);
    // advance 32 candidates = 512B = 64 f16x4 elements per iteration

    f32x16 zacc;
#pragma unroll
    for (int i = 0; i < 16; ++i) zacc[i] = 0.0f;
    float m0 = 1e30f, m1 = 1e30f, m2 = 1e30f, m3 = 1e30f;

    for (int it = 0; it < 16; ++it) {            // 16 iters x 32 candidates
        f16x4 a = *pA;
        pA += 64;
        f32x16 d0 = mfma8(a, bq0, zacc);
        f32x16 d1 = mfma8(a, bq1, zacc);
        m0 = fminf(m0, min16(d0));
        f32x16 d2 = mfma8(a, bq2, zacc);
        m1 = fminf(m1, min16(d1));
        f32x16 d3 = mfma8(a, bq3, zacc);
        m2 = fminf(m2, min16(d2));
        m3 = fminf(m3, min16(d3));
    }

    // ---- epilogue: merge lane-halves (rows split across l>>5), fold qsq ---
    m0 = fminf(m0, __shfl_xor(m0, 32, 64));
    m1 = fminf(m1, __shfl_xor(m1, 32, 64));
    m2 = fminf(m2, __shfl_xor(m2, 32, 64));
    m3 = fminf(m3, __shfl_xor(m3, 32, 64));
    if (!hi) {
        unsigned* __restrict__ kout = keys + (size_t)dir * BN;
        atomicMin(&kout[q0 + l31],      fkey(m0 + qsq0));
        atomicMin(&kout[q0 + 32 + l31], fkey(m1 + qsq1));
        atomicMin(&kout[q0 + 64 + l31], fkey(m2 + qsq2));
        atomicMin(&kout[q0 + 96 + l31], fkey(m3 + qsq3));
    }
}

// ---- finalize: decode key (qsq already folded in), global sum -------------
// grid: 2*BN/256 = 256 blocks
__global__ void __launch_bounds__(256)
finalize_kernel(const unsigned* __restrict__ keys, float* __restrict__ out) {
    __shared__ float red[4];
    const int idx = blockIdx.x * 256 + threadIdx.x;   // [0, 2*BN)

    float val = funkey(keys[idx]);

#pragma unroll
    for (int off = 32; off > 0; off >>= 1)
        val += __shfl_down(val, off, 64);

    const int wave = threadIdx.x >> 6;
    const int lane = threadIdx.x & 63;
    if (lane == 0) red[wave] = val;
    __syncthreads();
    if (threadIdx.x == 0)
        atomicAdd(out, red[0] + red[1] + red[2] + red[3]);
}

extern "C" void kernel_launch(void* const* d_in, const int* in_sizes, int n_in,
                              void* d_out, int out_size, void* d_ws, size_t ws_size,
                              hipStream_t stream) {
    const float* preds = (const float*)d_in[0];
    const float* gts   = (const float*)d_in[1];
    float* out = (float*)d_out;

    // ws layout: keys 256KB | cPackP 512KB | cPackG 512KB
    char* ws = (char*)d_ws;
    unsigned* keys = (unsigned*)ws;
    f16x8*    cP   = (f16x8*)(ws + (size_t)2 * BN * 4);
    f16x8*    cG   = cP + BN;

    dim3 gpack(BN / 256, 2);
    pack_kernel<<<gpack, 256, 0, stream>>>(preds, gts, cP, cG, keys, out);

    chamfer_mfma_kernel<<<2048, 256, 0, stream>>>(cP, cG, keys);

    finalize_kernel<<<2 * BN / 256, 256, 0, stream>>>(keys, out);
}